// Round 4
// baseline (236.763 us; speedup 1.0000x reference)
//
#include <hip/hip_runtime.h>
#include <hip/hip_bf16.h>
#include <cstdint>

// MultiHeadSelfAttention: B=4 S=4096 E=768 H=8 D=96. Inputs/outputs f32.
// Pipeline: f32->bf16 prepass (activations + weights) -> QKV GEMMs (both
// operands via global_load_lds, XOR-swizzled LDS) -> per-token 8x8 head-gram
// attention -> scrambled reshape -> output GEMM + bias (f32 out).

typedef unsigned short u16;
typedef short bf16x8 __attribute__((ext_vector_type(8)));
typedef float f32x4 __attribute__((ext_vector_type(4)));

#define B_  4
#define S_  4096
#define E_  768
#define H_  8
#define D_  96
#define T_  (B_*S_)            // 16384 tokens
#define BM_ 128
#define BN_ 64
#define NT_ (E_/BN_)           // 12 N-tiles

static __device__ __forceinline__ u16 f2bf(float f) {
  unsigned u = __builtin_bit_cast(unsigned, f);
  u += 0x7fffu + ((u >> 16) & 1u);           // round-to-nearest-even
  return (u16)(u >> 16);
}
static __device__ __forceinline__ unsigned pk2(float lo, float hi) {
  return (unsigned)f2bf(lo) | ((unsigned)f2bf(hi) << 16);
}
static __device__ __forceinline__ float bflo(unsigned u) {
  return __builtin_bit_cast(float, u << 16);
}
static __device__ __forceinline__ float bfhi(unsigned u) {
  return __builtin_bit_cast(float, u & 0xffff0000u);
}

// ---------------- f32 -> bf16 convert (activations), one tensor per launch
__global__ __launch_bounds__(256) void conv_bf16(
    const float* __restrict__ src, u16* __restrict__ dst)
{
  const int i = blockIdx.x * 256 + threadIdx.x;   // float4 index
  const float4 v = ((const float4*)src)[i];
  uint2 w;
  w.x = pk2(v.x, v.y);
  w.y = pk2(v.z, v.w);
  ((uint2*)dst)[i] = w;
}

// ---------------- f32 -> bf16 convert, all 4 weight matrices (E*E each)
__global__ __launch_bounds__(256) void conv_w(
    const float* __restrict__ w0, const float* __restrict__ w1,
    const float* __restrict__ w2, const float* __restrict__ w3,
    u16* __restrict__ dst)
{
  const int bpw = (E_ * E_ / 4) / 256;            // 576 blocks per weight
  const int which = blockIdx.x / bpw;
  const float* src = which == 0 ? w0 : which == 1 ? w1 : which == 2 ? w2 : w3;
  const int i = (blockIdx.x - which * bpw) * 256 + threadIdx.x;
  const float4 v = ((const float4*)src)[i];
  uint2 w;
  w.x = pk2(v.x, v.y);
  w.y = pk2(v.z, v.w);
  ((uint2*)(dst + (size_t)which * E_ * E_))[i] = w;
}

// ---------------- GEMM: C[T_,E_] = A[T_,E_](bf16) x W[E_,E_](bf16)^T (+bias)
// 128x64 tile, BK=64, 256 thr (4 waves 2x2, 64x32 each). Both operands via
// global_load_lds with source-side granule pre-swizzle (m173): granule(16B)
// g of row r lives at LDS slot g ^ (r&7). 24KB LDS -> 6 blocks/CU.
template<bool OUT_F32, bool BIAS>
__global__ __launch_bounds__(256, 6) void gemm_nt(
    const u16* __restrict__ A, const u16* __restrict__ W,
    const float* __restrict__ bias, void* __restrict__ Cv)
{
  __shared__ u16 lA[BM_ * 64];
  __shared__ u16 lB[BN_ * 64];
  const int tid  = threadIdx.x;
  const int wave = tid >> 6;
  const int lane = tid & 63;
  const int wr = wave >> 1, wc = wave & 1;       // 2x2 wave grid, 64x32/wave
  // XCD-chunked swizzle: 1536 blocks, 192/XCD -> 16 M-panels x 12 N per XCD
  const int bid = blockIdx.x;
  const int wg  = (bid & 7) * (gridDim.x >> 3) + (bid >> 3);
  const int mT  = wg / NT_;
  const int nT  = wg - mT * NT_;
  const int tM = mT * BM_, tN = nT * BN_;
  const int l15 = lane & 15, l4 = lane >> 4;

  f32x4 acc[4][2] = {};

  for (int kt = 0; kt < E_; kt += 64) {
    __syncthreads();  // prior-iter LDS reads done before overwrite
    // --- A tile 128x64 bf16 = 1024 granules(16B); 4 gload_lds/thread
#pragma unroll
    for (int c = 0; c < 4; ++c) {
      const int idx = (c << 8) + tid;
      const int r = idx >> 3, g = idx & 7;
      const int gs = g ^ (r & 7);
      const u16* ga = A + (tM + r) * E_ + kt + gs * 8;
      __builtin_amdgcn_global_load_lds(
          (const __attribute__((address_space(1))) void*)ga,
          (__attribute__((address_space(3))) void*)&lA[((c << 8) + (wave << 6)) << 3],
          16, 0, 0);
    }
    // --- B tile 64x64 bf16 = 512 granules; 2 gload_lds/thread
#pragma unroll
    for (int c = 0; c < 2; ++c) {
      const int idx = (c << 8) + tid;
      const int r = idx >> 3, g = idx & 7;
      const int gs = g ^ (r & 7);
      const u16* gb = W + (tN + r) * E_ + kt + gs * 8;
      __builtin_amdgcn_global_load_lds(
          (const __attribute__((address_space(1))) void*)gb,
          (__attribute__((address_space(3))) void*)&lB[((c << 8) + (wave << 6)) << 3],
          16, 0, 0);
    }
    __syncthreads();  // drains vmcnt(0) -> both tiles ready

#pragma unroll
    for (int kk = 0; kk < 2; ++kk) {
      bf16x8 a[4], b[2];
#pragma unroll
      for (int m = 0; m < 4; ++m) {
        const int rA = wr * 64 + m * 16 + l15;
        const int gA = (kk << 2) + l4;
        a[m] = *(const bf16x8*)&lA[rA * 64 + ((gA ^ (rA & 7)) << 3)];
      }
#pragma unroll
      for (int n = 0; n < 2; ++n) {
        const int rB = wc * 32 + n * 16 + l15;
        const int gB = (kk << 2) + l4;
        b[n] = *(const bf16x8*)&lB[rB * 64 + ((gB ^ (rB & 7)) << 3)];
      }
#pragma unroll
      for (int m = 0; m < 4; ++m)
#pragma unroll
        for (int n = 0; n < 2; ++n)
          acc[m][n] = __builtin_amdgcn_mfma_f32_16x16x32_bf16(a[m], b[n], acc[m][n], 0, 0, 0);
    }
  }

  // epilogue: C/D layout col=lane&15, row=(lane>>4)*4+reg  [m89/m91]
  const int cr = l4 * 4;
#pragma unroll
  for (int m = 0; m < 4; ++m) {
#pragma unroll
    for (int n = 0; n < 2; ++n) {
      const int row = tM + wr * 64 + m * 16 + cr;
      const int col = tN + wc * 32 + n * 16 + l15;
      const float badd = BIAS ? bias[col] : 0.f;
#pragma unroll
      for (int r = 0; r < 4; ++r) {
        const float val = acc[m][n][r] + badd;
        if constexpr (OUT_F32)
          ((float*)Cv)[(size_t)(row + r) * E_ + col] = val;
        else
          ((u16*)Cv)[(size_t)(row + r) * E_ + col] = f2bf(val);
      }
    }
  }
}

// ---------------- per-token attention: 1 wave per token
// att[i,j] = sum_d Q[t,i*96+d]*K[t,j*96+d]; masked softmax over j;
// out2D[b, 512*i + s/8, 96*(s%8)+d] = sum_j p[i,j]*V[t, j*96+d]
__global__ __launch_bounds__(256) void attn_tok(
    const u16* __restrict__ Q, const u16* __restrict__ K,
    const u16* __restrict__ V, const int* __restrict__ mask,
    u16* __restrict__ O)
{
  __shared__ float pl[4][8][8];
  const int tid = threadIdx.x, wave = tid >> 6, lane = tid & 63;
  const int t = blockIdx.x * 4 + wave;
  const int s = t & (S_ - 1);
  const int b = t >> 12;
  const int i = lane >> 3, j = lane & 7;

  const uint4* qp = (const uint4*)(Q + (size_t)t * E_ + i * D_);
  const uint4* kp = (const uint4*)(K + (size_t)t * E_ + j * D_);
  float acc = 0.f;
#pragma unroll
  for (int it = 0; it < 12; ++it) {   // 96 bf16 = 12 x uint4
    const uint4 qv = qp[it], kv = kp[it];
    acc += bflo(qv.x) * bflo(kv.x) + bfhi(qv.x) * bfhi(kv.x);
    acc += bflo(qv.y) * bflo(kv.y) + bfhi(qv.y) * bfhi(kv.y);
    acc += bflo(qv.z) * bflo(kv.z) + bfhi(qv.z) * bfhi(kv.z);
    acc += bflo(qv.w) * bflo(kv.w) + bfhi(qv.w) * bfhi(kv.w);
  }
  // mask==0 -> -1e20 everywhere -> softmax degenerates to 1/8
  float sv = (mask[t] == 0) ? -1e20f : acc;
  sv *= 0.03608439182435161f;          // 1/sqrt(768)
  float mx = sv;
  mx = fmaxf(mx, __shfl_xor(mx, 1));
  mx = fmaxf(mx, __shfl_xor(mx, 2));
  mx = fmaxf(mx, __shfl_xor(mx, 4));
  const float e = __expf(sv - mx);
  float sm = e;
  sm += __shfl_xor(sm, 1);
  sm += __shfl_xor(sm, 2);
  sm += __shfl_xor(sm, 4);
  pl[wave][i][j] = e / sm;
  __syncthreads();

  // PV: lane (i2, db) owns d = db*12 .. db*12+11 of head i2
  const int i2 = lane >> 3, db = lane & 7;
  float o[12] = {};
#pragma unroll
  for (int jj = 0; jj < 8; ++jj) {
    const float pj = pl[wave][i2][jj];
    const uint2* vp = (const uint2*)(V + (size_t)t * E_ + jj * D_ + db * 12);
    const uint2 v0 = vp[0], v1 = vp[1], v2 = vp[2];
    o[0]  += pj * bflo(v0.x);  o[1]  += pj * bfhi(v0.x);
    o[2]  += pj * bflo(v0.y);  o[3]  += pj * bfhi(v0.y);
    o[4]  += pj * bflo(v1.x);  o[5]  += pj * bfhi(v1.x);
    o[6]  += pj * bflo(v1.y);  o[7]  += pj * bfhi(v1.y);
    o[8]  += pj * bflo(v2.x);  o[9]  += pj * bfhi(v2.x);
    o[10] += pj * bflo(v2.y);  o[11] += pj * bfhi(v2.y);
  }
  // scrambled reshape [b,h,s,d] -> [b, 512h + s/8, 96(s%8)+d]
  const size_t row = (size_t)b * S_ + 512 * i2 + (s >> 3);
  u16* op = O + row * E_ + 96 * (s & 7) + db * 12;
  uint2 w0, w1, w2;
  w0.x = pk2(o[0], o[1]);
  w0.y = pk2(o[2], o[3]);
  w1.x = pk2(o[4], o[5]);
  w1.y = pk2(o[6], o[7]);
  w2.x = pk2(o[8], o[9]);
  w2.y = pk2(o[10], o[11]);
  ((uint2*)op)[0] = w0;
  ((uint2*)op)[1] = w1;
  ((uint2*)op)[2] = w2;
}

extern "C" void kernel_launch(void* const* d_in, const int* in_sizes, int n_in,
                              void* d_out, int out_size, void* d_ws, size_t ws_size,
                              hipStream_t stream)
{
  const float* values = (const float*)d_in[0];
  const float* keys   = (const float*)d_in[1];
  const float* query  = (const float*)d_in[2];
  const int*   mask   = (const int*)d_in[3];
  const float* Wv = (const float*)d_in[4];
  const float* Wk = (const float*)d_in[5];
  const float* Wq = (const float*)d_in[6];
  const float* Wo = (const float*)d_in[7];
  const float* bo = (const float*)d_in[8];

  const size_t TE = (size_t)T_ * E_;
  const size_t EE = (size_t)E_ * E_;
  u16* Qb = (u16*)d_ws;          // 25.2 MB each (bf16)
  u16* Kb = Qb + TE;
  u16* Vb = Kb + TE;
  u16* Xt = Vb + TE;             // A-convert scratch; later aliased as O2
  u16* Wb = Xt + TE;             // 4 x 1.18 MB bf16 weights (105.4 MB total)

  dim3 blk(256);
  dim3 gg(T_ / BM_ * NT_);       // 1536 blocks = 6/CU
  dim3 gc(TE / 4 / 256);         // 12288 blocks

  conv_w<<<dim3(4 * (E_ * E_ / 4) / 256), blk, 0, stream>>>(Wq, Wk, Wv, Wo, Wb);

  conv_bf16<<<gc, blk, 0, stream>>>(query, Xt);
  gemm_nt<false, false><<<gg, blk, 0, stream>>>(Xt, Wb + 0 * EE, nullptr, Qb);
  conv_bf16<<<gc, blk, 0, stream>>>(keys, Xt);
  gemm_nt<false, false><<<gg, blk, 0, stream>>>(Xt, Wb + 1 * EE, nullptr, Kb);
  conv_bf16<<<gc, blk, 0, stream>>>(values, Xt);
  gemm_nt<false, false><<<gg, blk, 0, stream>>>(Xt, Wb + 2 * EE, nullptr, Vb);

  attn_tok<<<dim3(T_ / 4), blk, 0, stream>>>(Qb, Kb, Vb, mask, Xt /*O2*/);

  gemm_nt<true, true><<<gg, blk, 0, stream>>>(Xt /*O2*/, Wb + 3 * EE, bo, (float*)d_out);
}

// Round 5
// 194.402 us; speedup vs baseline: 1.2179x; 1.2179x over previous
//
#include <hip/hip_runtime.h>
#include <hip/hip_bf16.h>
#include <cstdint>

// MultiHeadSelfAttention: B=4 S=4096 E=768 H=8 D=96. Inputs/outputs f32.
// Pipeline: f32->bf16 prepass (activations + weights) -> QKV GEMMs
// (2-phase double-buffered LDS, both operands via global_load_lds) ->
// per-token 8x8 head-gram attention -> scrambled reshape -> output GEMM
// + bias (f32 out).

typedef unsigned short u16;
typedef short bf16x8 __attribute__((ext_vector_type(8)));
typedef float f32x4 __attribute__((ext_vector_type(4)));

#define B_  4
#define S_  4096
#define E_  768
#define H_  8
#define D_  96
#define T_  (B_*S_)            // 16384 tokens
#define BM_ 128
#define BN_ 128
#define NT_ (E_/BN_)           // 6 N-tiles

static __device__ __forceinline__ u16 f2bf(float f) {
  unsigned u = __builtin_bit_cast(unsigned, f);
  u += 0x7fffu + ((u >> 16) & 1u);           // round-to-nearest-even
  return (u16)(u >> 16);
}
static __device__ __forceinline__ unsigned pk2(float lo, float hi) {
  return (unsigned)f2bf(lo) | ((unsigned)f2bf(hi) << 16);
}
static __device__ __forceinline__ float bflo(unsigned u) {
  return __builtin_bit_cast(float, u << 16);
}
static __device__ __forceinline__ float bfhi(unsigned u) {
  return __builtin_bit_cast(float, u & 0xffff0000u);
}

// ---------------- f32 -> bf16 convert (activations), one tensor per launch
__global__ __launch_bounds__(256) void conv_bf16(
    const float* __restrict__ src, u16* __restrict__ dst)
{
  const int i = blockIdx.x * 256 + threadIdx.x;   // float4 index
  const float4 v = ((const float4*)src)[i];
  uint2 w;
  w.x = pk2(v.x, v.y);
  w.y = pk2(v.z, v.w);
  ((uint2*)dst)[i] = w;
}

// ---------------- f32 -> bf16 convert, all 4 weight matrices (E*E each)
__global__ __launch_bounds__(256) void conv_w(
    const float* __restrict__ w0, const float* __restrict__ w1,
    const float* __restrict__ w2, const float* __restrict__ w3,
    u16* __restrict__ dst)
{
  const int bpw = (E_ * E_ / 4) / 256;            // 576 blocks per weight
  const int which = blockIdx.x / bpw;
  const float* src = which == 0 ? w0 : which == 1 ? w1 : which == 2 ? w2 : w3;
  const int i = (blockIdx.x - which * bpw) * 256 + threadIdx.x;
  const float4 v = ((const float4*)src)[i];
  uint2 w;
  w.x = pk2(v.x, v.y);
  w.y = pk2(v.z, v.w);
  ((uint2*)(dst + (size_t)which * E_ * E_))[i] = w;
}

// ---------------- GEMM: C[T_,E_] = A[T_,E_](bf16) x W[E_,E_](bf16)^T (+bias)
// 128x128 tile, BK=32, 4 waves (2x2 grid, 64x64 wave tile), 16x16x32 MFMA.
// 2-phase double-buffered LDS: frag-reads(buf) -> issue STAGE(buf^1, t+1)
// -> MFMA -> barrier. Granule swizzle: 16B-granule g of row r stored at
// slot g ^ ((r>>1)&3) -> 2-way-max bank conflicts on ds_read_b128.
#define STAGE(BUF, KT)                                                         \
  {                                                                            \
    _Pragma("unroll")                                                          \
    for (int c = 0; c < 2; ++c) {                                              \
      const int idx = (c << 8) + tid;                                          \
      const int r = idx >> 2, g = idx & 3;                                     \
      const int gs = g ^ ((r >> 1) & 3);                                       \
      __builtin_amdgcn_global_load_lds(                                        \
          (const __attribute__((address_space(1))) void*)                     \
              (A + (size_t)(tM + r) * E_ + (KT) + (gs << 3)),                  \
          (__attribute__((address_space(3))) void*)                           \
              &lds[BUF][0][((c << 8) + (wave << 6)) << 3], 16, 0, 0);          \
      __builtin_amdgcn_global_load_lds(                                        \
          (const __attribute__((address_space(1))) void*)                     \
              (Wt + (size_t)(tN + r) * E_ + (KT) + (gs << 3)),                 \
          (__attribute__((address_space(3))) void*)                           \
              &lds[BUF][1][((c << 8) + (wave << 6)) << 3], 16, 0, 0);          \
    }                                                                          \
  }

#define LOADFRAGS(BUF)                                                         \
  {                                                                            \
    _Pragma("unroll")                                                          \
    for (int m = 0; m < 4; ++m)                                                \
      a[m] = *(const bf16x8*)&lds[BUF][0][((wr << 6) + (m << 4) + l15) * 32 + slotOff]; \
    _Pragma("unroll")                                                          \
    for (int n = 0; n < 4; ++n)                                                \
      b[n] = *(const bf16x8*)&lds[BUF][1][((wc << 6) + (n << 4) + l15) * 32 + slotOff]; \
  }

#define DOMFMA()                                                               \
  {                                                                            \
    _Pragma("unroll")                                                          \
    for (int m = 0; m < 4; ++m)                                                \
      _Pragma("unroll")                                                        \
      for (int n = 0; n < 4; ++n)                                              \
        acc[m][n] = __builtin_amdgcn_mfma_f32_16x16x32_bf16(a[m], b[n], acc[m][n], 0, 0, 0); \
  }

template<bool OUT_F32, bool BIAS>
__global__ __launch_bounds__(256, 3) void gemm_nt(
    const u16* __restrict__ A, const u16* __restrict__ Wt,
    const float* __restrict__ bias, void* __restrict__ Cv)
{
  __shared__ u16 lds[2][2][BM_ * 32];            // [buf][A/B][128x32] = 32KB
  const int tid  = threadIdx.x;
  const int wave = tid >> 6;
  const int lane = tid & 63;
  const int wr = wave >> 1, wc = wave & 1;       // 2x2 wave grid, 64x64/wave
  // XCD-chunked swizzle: 768 blocks, 96/XCD -> 16 M-panels x 6 N per XCD
  const int bid = blockIdx.x;
  const int wg  = (bid & 7) * (gridDim.x >> 3) + (bid >> 3);
  const int mT  = wg / NT_;
  const int nT  = wg - mT * NT_;
  const int tM = mT * BM_, tN = nT * BN_;
  const int l15 = lane & 15, l4 = lane >> 4;
  const int slotOff = (l4 ^ ((l15 >> 1) & 3)) << 3;

  f32x4 acc[4][4] = {};

  STAGE(0, 0);
  __syncthreads();

  for (int i = 0; i < 12; ++i) {
    const int kt = i << 6;
    {
      bf16x8 a[4], b[4];
      LOADFRAGS(0);
      STAGE(1, kt + 32);
      DOMFMA();
    }
    __syncthreads();
    {
      bf16x8 a[4], b[4];
      LOADFRAGS(1);
      if (i < 11) STAGE(0, kt + 64);
      DOMFMA();
    }
    __syncthreads();
  }

  // epilogue: C/D layout col=lane&15, row=(lane>>4)*4+reg  [m89/m91]
  if constexpr (OUT_F32) {
    // f32 direct stores: 16 lanes x 4B contiguous -> full 64B lines
#pragma unroll
    for (int m = 0; m < 4; ++m) {
#pragma unroll
      for (int n = 0; n < 4; ++n) {
        const int row = tM + (wr << 6) + (m << 4) + (l4 << 2);
        const int col = tN + (wc << 6) + (n << 4) + l15;
        const float badd = BIAS ? bias[col] : 0.f;
#pragma unroll
        for (int r = 0; r < 4; ++r)
          ((float*)Cv)[(size_t)(row + r) * E_ + col] = acc[m][n][r] + badd;
      }
    }
  } else {
    // bf16: stage C tile (128x128 u16 = 32KB) in LDS, write back coalesced
    __syncthreads();
    u16* lC = (u16*)lds;
#pragma unroll
    for (int m = 0; m < 4; ++m)
#pragma unroll
      for (int n = 0; n < 4; ++n) {
        const int row = (wr << 6) + (m << 4) + (l4 << 2);
        const int col = (wc << 6) + (n << 4) + l15;
#pragma unroll
        for (int r = 0; r < 4; ++r)
          lC[(row + r) * BN_ + col] = f2bf(acc[m][n][r]);
      }
    __syncthreads();
#pragma unroll
    for (int p = 0; p < 8; ++p) {
      const int row = (p << 4) + (wave << 2) + l4;   // 16 rows per pass
      const bf16x8 v = *(const bf16x8*)&lC[row * BN_ + (l15 << 3)];
      *(bf16x8*)((u16*)Cv + (size_t)(tM + row) * E_ + tN + (l15 << 3)) = v;
    }
  }
}

// ---------------- per-token attention: 1 wave per token
// att[i,j] = sum_d Q[t,i*96+d]*K[t,j*96+d]; masked softmax over j;
// out2D[b, 512*i + s/8, 96*(s%8)+d] = sum_j p[i,j]*V[t, j*96+d]
__global__ __launch_bounds__(256) void attn_tok(
    const u16* __restrict__ Q, const u16* __restrict__ K,
    const u16* __restrict__ V, const int* __restrict__ mask,
    u16* __restrict__ O)
{
  __shared__ float pl[4][8][8];
  const int tid = threadIdx.x, wave = tid >> 6, lane = tid & 63;
  const int t = blockIdx.x * 4 + wave;
  const int s = t & (S_ - 1);
  const int b = t >> 12;
  const int i = lane >> 3, j = lane & 7;

  const uint4* qp = (const uint4*)(Q + (size_t)t * E_ + i * D_);
  const uint4* kp = (const uint4*)(K + (size_t)t * E_ + j * D_);
  float acc = 0.f;
#pragma unroll
  for (int it = 0; it < 12; ++it) {   // 96 bf16 = 12 x uint4
    const uint4 qv = qp[it], kv = kp[it];
    acc += bflo(qv.x) * bflo(kv.x) + bfhi(qv.x) * bfhi(kv.x);
    acc += bflo(qv.y) * bflo(kv.y) + bfhi(qv.y) * bfhi(kv.y);
    acc += bflo(qv.z) * bflo(kv.z) + bfhi(qv.z) * bfhi(kv.z);
    acc += bflo(qv.w) * bflo(kv.w) + bfhi(qv.w) * bfhi(kv.w);
  }
  // mask==0 -> -1e20 everywhere -> softmax degenerates to 1/8
  float sv = (mask[t] == 0) ? -1e20f : acc;
  sv *= 0.03608439182435161f;          // 1/sqrt(768)
  float mx = sv;
  mx = fmaxf(mx, __shfl_xor(mx, 1));
  mx = fmaxf(mx, __shfl_xor(mx, 2));
  mx = fmaxf(mx, __shfl_xor(mx, 4));
  const float e = __expf(sv - mx);
  float sm = e;
  sm += __shfl_xor(sm, 1);
  sm += __shfl_xor(sm, 2);
  sm += __shfl_xor(sm, 4);
  pl[wave][i][j] = e / sm;
  __syncthreads();

  // PV: lane (i2, db) owns d = db*12 .. db*12+11 of head i2
  const int i2 = lane >> 3, db = lane & 7;
  float o[12] = {};
#pragma unroll
  for (int jj = 0; jj < 8; ++jj) {
    const float pj = pl[wave][i2][jj];
    const uint2* vp = (const uint2*)(V + (size_t)t * E_ + jj * D_ + db * 12);
    const uint2 v0 = vp[0], v1 = vp[1], v2 = vp[2];
    o[0]  += pj * bflo(v0.x);  o[1]  += pj * bfhi(v0.x);
    o[2]  += pj * bflo(v0.y);  o[3]  += pj * bfhi(v0.y);
    o[4]  += pj * bflo(v1.x);  o[5]  += pj * bfhi(v1.x);
    o[6]  += pj * bflo(v1.y);  o[7]  += pj * bfhi(v1.y);
    o[8]  += pj * bflo(v2.x);  o[9]  += pj * bfhi(v2.x);
    o[10] += pj * bflo(v2.y);  o[11] += pj * bfhi(v2.y);
  }
  // scrambled reshape [b,h,s,d] -> [b, 512h + s/8, 96(s%8)+d]
  const size_t row = (size_t)b * S_ + 512 * i2 + (s >> 3);
  u16* op = O + row * E_ + 96 * (s & 7) + db * 12;
  uint2 w0, w1, w2;
  w0.x = pk2(o[0], o[1]);
  w0.y = pk2(o[2], o[3]);
  w1.x = pk2(o[4], o[5]);
  w1.y = pk2(o[6], o[7]);
  w2.x = pk2(o[8], o[9]);
  w2.y = pk2(o[10], o[11]);
  ((uint2*)op)[0] = w0;
  ((uint2*)op)[1] = w1;
  ((uint2*)op)[2] = w2;
}

extern "C" void kernel_launch(void* const* d_in, const int* in_sizes, int n_in,
                              void* d_out, int out_size, void* d_ws, size_t ws_size,
                              hipStream_t stream)
{
  const float* values = (const float*)d_in[0];
  const float* keys   = (const float*)d_in[1];
  const float* query  = (const float*)d_in[2];
  const int*   mask   = (const int*)d_in[3];
  const float* Wv = (const float*)d_in[4];
  const float* Wk = (const float*)d_in[5];
  const float* Wq = (const float*)d_in[6];
  const float* Wo = (const float*)d_in[7];
  const float* bo = (const float*)d_in[8];

  const size_t TE = (size_t)T_ * E_;
  const size_t EE = (size_t)E_ * E_;
  u16* Qb = (u16*)d_ws;          // 25.2 MB each (bf16)
  u16* Kb = Qb + TE;
  u16* Vb = Kb + TE;
  u16* Xt = Vb + TE;             // A-convert scratch; later aliased as O2
  u16* Wb = Xt + TE;             // 4 x 1.18 MB bf16 weights (105.4 MB total)

  dim3 blk(256);
  dim3 gg(T_ / BM_ * NT_);       // 768 blocks = 3/CU, one cohort
  dim3 gc(TE / 4 / 256);         // 12288 blocks

  conv_w<<<dim3(4 * (E_ * E_ / 4) / 256), blk, 0, stream>>>(Wq, Wk, Wv, Wo, Wb);

  conv_bf16<<<gc, blk, 0, stream>>>(query, Xt);
  gemm_nt<false, false><<<gg, blk, 0, stream>>>(Xt, Wb + 0 * EE, nullptr, Qb);
  conv_bf16<<<gc, blk, 0, stream>>>(keys, Xt);
  gemm_nt<false, false><<<gg, blk, 0, stream>>>(Xt, Wb + 1 * EE, nullptr, Kb);
  conv_bf16<<<gc, blk, 0, stream>>>(values, Xt);
  gemm_nt<false, false><<<gg, blk, 0, stream>>>(Xt, Wb + 2 * EE, nullptr, Vb);

  attn_tok<<<dim3(T_ / 4), blk, 0, stream>>>(Qb, Kb, Vb, mask, Xt /*O2*/);

  gemm_nt<true, true><<<gg, blk, 0, stream>>>(Xt /*O2*/, Wb + 3 * EE, bo, (float*)d_out);
}